// Round 14
// baseline (239.575 us; speedup 1.0000x reference)
//
#include <hip/hip_runtime.h>
#include <hip/hip_fp16.h>
#include <math.h>

#define NN 100000
#define NE 1600000
#define D  64
#define NBLK 391  // ceil(NN/256)

typedef _Float16 half2v __attribute__((ext_vector_type(2)));

// in-register packed entry: [col:17][ex_fp16_no_sign:15]  (col < 2^17, ex in (0,1])
__device__ __forceinline__ unsigned int pack_entry(int col, float ex) {
    unsigned short hb = __half_as_ushort(__float2half(ex));
    return ((unsigned int)col << 15) | (unsigned int)(hb & 0x7FFFu);
}
__device__ __forceinline__ float unpack_ex(unsigned int pk) {
    return __half2float(__ushort_as_half((unsigned short)(pk & 0x7FFFu)));
}

__device__ __forceinline__ float dot2acc(int a, unsigned int b, float c) {
#if defined(__has_builtin) && __has_builtin(__builtin_amdgcn_fdot2)
    return __builtin_amdgcn_fdot2(__builtin_bit_cast(half2v, a),
                                  __builtin_bit_cast(half2v, b), c, false);
#else
    float2 fa = __half22float2(*(const __half2*)&a);
    float2 fb = __half22float2(*(const __half2*)&b);
    return fmaf(fa.y, fb.y, fmaf(fa.x, fb.x, c));
#endif
}

// ---------------- K_prep_count: zx[n][0:64]=z/||z||, zx[n][64:128]=x@W^T (fp16);
//                  count phase into per-virtual-XCD histogram cnt8[bid&7][r] ----------------
__global__ __launch_bounds__(256) void k_prep_count(const float* __restrict__ z,
                                                    const float* __restrict__ x,
                                                    const float* __restrict__ W,
                                                    __half* __restrict__ zx,
                                                    const int* __restrict__ ei,
                                                    int* __restrict__ cnt8,
                                                    unsigned int* __restrict__ rankr) {
    __shared__ unsigned int WtP[32 * 64];  // WtP[d2*64 + j] = half2(W[j][2*d2], W[j][2*d2+1]), 8 KB
    {
        const float2* W2 = (const float2*)W;
        for (int i = threadIdx.x; i < 2048; i += 256) {
            int j = i >> 5, d2 = i & 31;
            float2 wp = W2[j * 32 + d2];  // coalesced pair read of row j
            half2v h;
            h.x = (_Float16)wp.x;
            h.y = (_Float16)wp.y;
            WtP[d2 * 64 + j] = __builtin_bit_cast(unsigned int, h);
        }
    }
    __syncthreads();
    const int lane = threadIdx.x & 63;
    int wave = blockIdx.x * 4 + (threadIdx.x >> 6);
    int nWaves = gridDim.x * 4;
    for (int n = wave; n < NN; n += nWaves) {
        float zv = z[n * D + lane];
        float s = zv * zv;
#pragma unroll
        for (int off = 32; off; off >>= 1) s += __shfl_xor(s, off);
        float inv = 1.0f / sqrtf(fmaxf(s, 1e-18f));
        zx[(size_t)n * 128 + lane] = __float2half(zv * inv);
        // pack x row into lane-held half2 pairs: lane i holds (x[2*(i&31)], x[2*(i&31)+1])
        float xv = x[n * D + lane];
        float pa = __shfl(xv, 2 * (lane & 31));
        float pb = __shfl(xv, 2 * (lane & 31) + 1);
        half2v pkh;
        pkh.x = (_Float16)pa;
        pkh.y = (_Float16)pb;
        int pki = __builtin_bit_cast(int, pkh);
        float y0 = 0.0f, y1 = 0.0f;
#pragma unroll
        for (int d2 = 0; d2 < 32; d2 += 2) {
            int pv0 = __shfl(pki, d2);
            int pv1 = __shfl(pki, d2 + 1);
            unsigned int wv0 = WtP[d2 * 64 + lane];
            unsigned int wv1 = WtP[(d2 + 1) * 64 + lane];
            y0 = dot2acc(pv0, wv0, y0);
            y1 = dot2acc(pv1, wv1, y1);
        }
        zx[(size_t)n * 128 + 64 + lane] = __float2half(y0 + y1);
    }
    // ---- count phase: per-virtual-XCD histogram (cnt8 pre-zeroed) ----
    const int myc = (blockIdx.x & 7) * NN;
    const unsigned int xcdbits = (unsigned int)(blockIdx.x & 7) << 12;
    int i = blockIdx.x * 256 + threadIdx.x;
    int stride = gridDim.x * 256;
    for (int e = i; e < NE; e += stride) {
        int r = __builtin_nontemporal_load(&ei[e]);
        int rk = atomicAdd(&cnt8[myc + r], 1);
        // [r:17][xcd:3][rank:12]
        __builtin_nontemporal_store(((unsigned int)r << 15) | xcdbits | (unsigned int)rk,
                                    &rankr[e]);
    }
}

// ---------------- scan: exclusive prefix sum over row totals ----------------
__global__ __launch_bounds__(256) void k_scan1(const int* __restrict__ cnt8,
                                               int* __restrict__ inc,
                                               int* __restrict__ bsum) {
    __shared__ int sh[256];
    int gid = blockIdx.x * 256 + threadIdx.x;
    int v = 0;
    if (gid < NN) {
#pragma unroll
        for (int k = 0; k < 8; ++k) v += cnt8[k * NN + gid];
    }
    sh[threadIdx.x] = v;
    __syncthreads();
    for (int off = 1; off < 256; off <<= 1) {
        int t = (threadIdx.x >= off) ? sh[threadIdx.x - off] : 0;
        __syncthreads();
        sh[threadIdx.x] += t;
        __syncthreads();
    }
    if (gid < NN) inc[gid] = sh[threadIdx.x];
    if (threadIdx.x == 255) bsum[blockIdx.x] = sh[255];
}

__global__ __launch_bounds__(512) void k_scan2(int* __restrict__ bsum) {
    __shared__ int sh[512];
    int v = (threadIdx.x < NBLK) ? bsum[threadIdx.x] : 0;
    sh[threadIdx.x] = v;
    __syncthreads();
    for (int off = 1; off < 512; off <<= 1) {
        int t = (threadIdx.x >= off) ? sh[threadIdx.x - off] : 0;
        __syncthreads();
        sh[threadIdx.x] += t;
        __syncthreads();
    }
    if (threadIdx.x < NBLK) bsum[threadIdx.x] = sh[threadIdx.x] - v;  // exclusive
}

__global__ __launch_bounds__(256) void k_scan3(const int* __restrict__ cnt8,
                                               const int* __restrict__ inc,
                                               const int* __restrict__ bsum,
                                               int* __restrict__ row_start,
                                               int* __restrict__ row_start8,
                                               int* __restrict__ tot) {
    int gid = blockIdx.x * 256 + threadIdx.x;
    if (gid >= NN) return;
    int c[8];
    int s8 = 0;
#pragma unroll
    for (int k = 0; k < 8; ++k) {
        c[k] = cnt8[k * NN + gid];
        s8 += c[k];
    }
    int ex = inc[gid] - s8 + bsum[blockIdx.x];
    row_start[gid] = ex;
    tot[gid] = s8;
    int base = ex;
#pragma unroll
    for (int k = 0; k < 8; ++k) {
        row_start8[k * NN + gid] = base;
        base += c[k];
    }
}

// ---------------- K_place: atomic-free colidx scatter via per-XCD offsets ----------------
__global__ __launch_bounds__(256) void k_place(const int* __restrict__ ei,
                                               const unsigned int* __restrict__ rankr,
                                               const int* __restrict__ row_start8,
                                               int* __restrict__ colidx) {
    int e = blockIdx.x * 256 + threadIdx.x;
    if (e >= NE) return;
    unsigned int rr = __builtin_nontemporal_load(&rankr[e]);
    int c = __builtin_nontemporal_load(&ei[NE + e]);
    int r = (int)(rr >> 15);
    int xcd = (int)((rr >> 12) & 7u);
    int rk = (int)(rr & 0xFFFu);
    __builtin_nontemporal_store(c, &colidx[row_start8[xcd * NN + r] + rk]);
}

// ---------------- K_node: 4 nodes/wave; phase B does 2 edges per load (half2 per lane) ----------------
__global__ __launch_bounds__(256) void k_node(const __half* __restrict__ zx,
                                              const int* __restrict__ colidx,
                                              const int* __restrict__ row_start,
                                              const int* __restrict__ tot,
                                              const float* __restrict__ b,
                                              const float* __restrict__ alpha_p,
                                              const float* __restrict__ bias_p,
                                              float* __restrict__ out) {
    const int lane = threadIdx.x & 63;
    const int sub = lane & 15;   // edge slot within my node's group
    const int hh = lane >> 5;    // 0: even edge of pair, 1: odd edge
    const int hl = lane & 31;    // dim-pair index within half
    int w = (blockIdx.x * blockDim.x + threadIdx.x) >> 6;
    int nb = w * 4;  // 4 nodes per wave; grid exact
    int n = nb + (lane >> 4);
    const float alpha = *alpha_p;
    const float bias = *bias_p;
    const float Mest = fabsf(alpha) + bias;  // >= max logit since |corr| <= 1
    int rs = row_start[n];
    int c = tot[n];
    float bv = b[lane];
    const float4* zi4 = (const float4*)(zx + (size_t)n * 128);
    float4 zi[8];
#pragma unroll
    for (int k = 0; k < 8; ++k) zi[k] = zi4[k];
    int cmax = c;
    cmax = max(cmax, __shfl_xor(cmax, 16));
    cmax = max(cmax, __shfl_xor(cmax, 32));
    // per-group accumulators: lane holds dims (2*hl, 2*hl+1); halves folded at end
    float2 g0 = {0.f, 0.f}, g1 = {0.f, 0.f}, g2 = {0.f, 0.f}, g3 = {0.f, 0.f};
    float exsum = 0.0f;  // per-slot-lane; reduced once at end
    for (int base = 0; base < cmax; base += 16) {
        int idx = base + sub;
        bool valid = idx < c;
        int col = valid ? colidx[rs + idx] : 0;
        // ---- phase A: in-lane dot(zn[n], zn[col]), 4 independent fdot2 chains ----
        const float4* zj4 = (const float4*)(zx + (size_t)col * 128);
        float4 zj[8];
#pragma unroll
        for (int k = 0; k < 8; ++k) zj[k] = zj4[k];
        float d0 = 0.0f, d1 = 0.0f, d2 = 0.0f, d3 = 0.0f;
#pragma unroll
        for (int k = 0; k < 8; ++k) {
            const int* ha = (const int*)&zi[k];
            const unsigned int* hb = (const unsigned int*)&zj[k];
            d0 = dot2acc(ha[0], hb[0], d0);
            d1 = dot2acc(ha[1], hb[1], d1);
            d2 = dot2acc(ha[2], hb[2], d2);
            d3 = dot2acc(ha[3], hb[3], d3);
        }
        float dot = (d0 + d1) + (d2 + d3);
        float ex = valid ? __expf(alpha * dot + bias - Mest) : 0.0f;
        exsum += ex;
        unsigned int pk = pack_entry(col, ex);
        // ---- phase B: 2 edges per load; lanes 0-31 edge j, lanes 32-63 edge j+1 ----
#define PHASE_B(GG, ACC)                                                                           \
        {                                                                                          \
            int cg = __shfl(c, GG * 16);                                                           \
            int mg = cg - base;                                                                    \
            mg = mg > 16 ? 16 : mg;                                                                \
            int j = 0;                                                                             \
            for (; j + 4 <= mg; j += 4) {                                                          \
                int q00 = __builtin_amdgcn_readlane((int)pk, GG * 16 + j);                         \
                int q01 = __builtin_amdgcn_readlane((int)pk, GG * 16 + j + 1);                     \
                int q10 = __builtin_amdgcn_readlane((int)pk, GG * 16 + j + 2);                     \
                int q11 = __builtin_amdgcn_readlane((int)pk, GG * 16 + j + 3);                     \
                unsigned int qa = (unsigned int)(hh ? q01 : q00);                                  \
                unsigned int qb = (unsigned int)(hh ? q11 : q10);                                  \
                unsigned int va = *(const unsigned int*)(zx + (size_t)(qa >> 15) * 128 + 64 + 2 * hl); \
                unsigned int vb = *(const unsigned int*)(zx + (size_t)(qb >> 15) * 128 + 64 + 2 * hl); \
                float ea = unpack_ex(qa), eb = unpack_ex(qb);                                      \
                float2 fa = __half22float2(*(const __half2*)&va);                                  \
                float2 fb = __half22float2(*(const __half2*)&vb);                                  \
                ACC.x = fmaf(ea, fa.x, ACC.x);                                                     \
                ACC.y = fmaf(ea, fa.y, ACC.y);                                                     \
                ACC.x = fmaf(eb, fb.x, ACC.x);                                                     \
                ACC.y = fmaf(eb, fb.y, ACC.y);                                                     \
            }                                                                                      \
            for (; j < mg; j += 2) {                                                               \
                int q00 = __builtin_amdgcn_readlane((int)pk, GG * 16 + j);                         \
                int q01 = __builtin_amdgcn_readlane((int)pk, GG * 16 + j + 1);                     \
                unsigned int qa = (unsigned int)(hh ? q01 : q00);                                  \
                unsigned int va = *(const unsigned int*)(zx + (size_t)(qa >> 15) * 128 + 64 + 2 * hl); \
                float ea = unpack_ex(qa);                                                          \
                float2 fa = __half22float2(*(const __half2*)&va);                                  \
                ACC.x = fmaf(ea, fa.x, ACC.x);                                                     \
                ACC.y = fmaf(ea, fa.y, ACC.y);                                                     \
            }                                                                                      \
        }
        PHASE_B(0, g0)
        PHASE_B(1, g1)
        PHASE_B(2, g2)
        PHASE_B(3, g3)
#undef PHASE_B
    }
    // denom: one 16-lane butterfly
    exsum += __shfl_xor(exsum, 1);
    exsum += __shfl_xor(exsum, 2);
    exsum += __shfl_xor(exsum, 4);
    exsum += __shfl_xor(exsum, 8);
    float dg0 = __shfl(exsum, 0);
    float dg1 = __shfl(exsum, 16);
    float dg2 = __shfl(exsum, 32);
    float dg3 = __shfl(exsum, 48);
    // fold halves and repack to dim=lane layout
#define FINISH(ACC, DG, ROW)                                                    \
    {                                                                           \
        ACC.x += __shfl_xor(ACC.x, 32);                                         \
        ACC.y += __shfl_xor(ACC.y, 32);                                         \
        float vx = __shfl(ACC.x, lane >> 1);                                    \
        float vy = __shfl(ACC.y, lane >> 1);                                    \
        float a = (lane & 1) ? vy : vx;                                         \
        out[(size_t)(ROW) * D + lane] = a / (DG + 1e-9f) + bv;                  \
    }
    FINISH(g0, dg0, nb + 0)
    FINISH(g1, dg1, nb + 1)
    FINISH(g2, dg2, nb + 2)
    FINISH(g3, dg3, nb + 3)
#undef FINISH
}

extern "C" void kernel_launch(void* const* d_in, const int* in_sizes, int n_in,
                              void* d_out, int out_size, void* d_ws, size_t ws_size,
                              hipStream_t stream) {
    const float* x = (const float*)d_in[0];
    const int* ei = (const int*)d_in[1];  // [2, NE] int32
    const float* z = (const float*)d_in[2];
    const float* W = (const float*)d_in[3];
    const float* b = (const float*)d_in[4];
    const float* alpha = (const float*)d_in[5];
    const float* bias_edge = (const float*)d_in[6];
    float* out = (float*)d_out;  // [NN, D]

    // workspace layout (~46 MB)
    char* ws = (char*)d_ws;
    size_t off = 0;
    __half* zx = (__half*)(ws + off); off += (size_t)NN * 128 * 2;           // 25.6 MB
    int* colidx = (int*)(ws + off); off += (size_t)NE * 4;                   // 6.4 MB
    unsigned int* rankr = (unsigned int*)(ws + off); off += (size_t)NE * 4;  // 6.4 MB
    int* cnt8 = (int*)(ws + off); off += (size_t)8 * NN * 4;                 // 3.2 MB
    int* row_start8 = (int*)(ws + off); off += (size_t)8 * NN * 4;           // 3.2 MB
    int* inc = (int*)(ws + off); off += (size_t)NN * 4;
    int* row_start = (int*)(ws + off); off += (size_t)NN * 4;
    int* tot = (int*)(ws + off); off += (size_t)NN * 4;
    int* bsum = (int*)(ws + off); off += 512 * 4;

    hipMemsetAsync(cnt8, 0, (size_t)8 * NN * 4, stream);
    k_prep_count<<<4096, 256, 0, stream>>>(z, x, W, zx, ei, cnt8, rankr);
    k_scan1<<<NBLK, 256, 0, stream>>>(cnt8, inc, bsum);
    k_scan2<<<1, 512, 0, stream>>>(bsum);
    k_scan3<<<NBLK, 256, 0, stream>>>(cnt8, inc, bsum, row_start, row_start8, tot);
    k_place<<<(NE + 255) / 256, 256, 0, stream>>>(ei, rankr, row_start8, colidx);
    // 4 nodes per wave, 16 nodes per 256-thread block -> exactly NN/16 = 6250 blocks
    k_node<<<NN / 16, 256, 0, stream>>>(zx, colidx, row_start, tot, b, alpha, bias_edge, out);
}